// Round 1
// baseline (1285.451 us; speedup 1.0000x reference)
//
#include <hip/hip_runtime.h>
#include <hip/hip_bf16.h>

#define NNODES 20000
#define NEDGES 640000
#define DIM 256
#define ND (NNODES * DIM)          // 5,120,000 floats per node-feature matrix
#define BN_EPS 1e-5f

// ---------------------------------------------------------------- utilities
__global__ void zero_i(int* __restrict__ p, int n) {
    int i = blockIdx.x * blockDim.x + threadIdx.x;
    if (i < n) p[i] = 0;
}
__global__ void zero_f(float* __restrict__ p, int n) {
    int i = blockIdx.x * blockDim.x + threadIdx.x;
    if (i < n) p[i] = 0.f;
}

// ---------------------------------------------------------------- CSR build
__global__ void hist_k(const int* __restrict__ dst, int* __restrict__ deg) {
    int e = blockIdx.x * blockDim.x + threadIdx.x;
    if (e < NEDGES) atomicAdd(&deg[dst[e]], 1);
}

// single-block exclusive scan of deg[0..NNODES) -> off, cursor; off[NNODES]=E
__global__ void scan_k(const int* __restrict__ deg, int* __restrict__ off,
                       int* __restrict__ cursor) {
    __shared__ int sm[1024];
    __shared__ int carry_s;
    const int t = threadIdx.x;
    if (t == 0) carry_s = 0;
    __syncthreads();
    for (int base = 0; base < NNODES; base += 1024) {
        int i = base + t;
        int val = (i < NNODES) ? deg[i] : 0;
        sm[t] = val;
        __syncthreads();
        for (int ofs = 1; ofs < 1024; ofs <<= 1) {
            int add = (t >= ofs) ? sm[t - ofs] : 0;
            __syncthreads();
            sm[t] += add;
            __syncthreads();
        }
        int inc = sm[t];
        int carry = carry_s;
        int exc = carry + inc - val;
        if (i < NNODES) { off[i] = exc; cursor[i] = exc; }
        __syncthreads();
        if (t == 1023) carry_s = carry + sm[1023];
        __syncthreads();
    }
    if (t == 0) off[NNODES] = carry_s;
}

__global__ void scatter_k(const int* __restrict__ src, const int* __restrict__ dst,
                          int* __restrict__ cursor, int* __restrict__ ssrc) {
    int e = blockIdx.x * blockDim.x + threadIdx.x;
    if (e < NEDGES) {
        int d = dst[e];
        int pos = atomicAdd(&cursor[d], 1);
        ssrc[pos] = src[e];
    }
}

// ---------------------------------------------------------------- fused QKVS GEMM
// out[mat] (N x 256) = X (N x 256) @ W[mat] (256 x 256) + b[mat]
// grid: (ceil(N/128), 8)  — blockIdx.y: mat = y>>1, col-half = y&1
// block: 256 threads, 8x8 microtile each -> 128x128 C tile
__launch_bounds__(256, 2)
__global__ void gemm_qkvs(const float* __restrict__ X,
                          const float* __restrict__ Wq, const float* __restrict__ Wk,
                          const float* __restrict__ Wv, const float* __restrict__ Ws,
                          const float* __restrict__ bq, const float* __restrict__ bk,
                          const float* __restrict__ bv, const float* __restrict__ bs,
                          float* __restrict__ oq, float* __restrict__ ok,
                          float* __restrict__ ov, float* __restrict__ os) {
    __shared__ float As[16][132];   // [k][m], padded
    __shared__ float Bs[16][132];   // [k][n], padded

    const int mat = blockIdx.y >> 1;
    const int n0  = (blockIdx.y & 1) * 128;
    const int m0  = blockIdx.x * 128;

    const float* W    = (mat == 0) ? Wq : (mat == 1) ? Wk : (mat == 2) ? Wv : Ws;
    const float* bias = (mat == 0) ? bq : (mat == 1) ? bk : (mat == 2) ? bv : bs;
    float*       out  = (mat == 0) ? oq : (mat == 1) ? ok : (mat == 2) ? ov : os;

    const int tid = threadIdx.x;
    const int tx = tid & 15;   // col group (8 cols each)
    const int ty = tid >> 4;   // row group (8 rows each)

    float acc[8][8];
    #pragma unroll
    for (int i = 0; i < 8; ++i)
        #pragma unroll
        for (int j = 0; j < 8; ++j) acc[i][j] = 0.f;

    for (int k0 = 0; k0 < 256; k0 += 16) {
        // A tile: 128 rows x 16 k = 512 float4, 2 per thread; store transposed
        #pragma unroll
        for (int i = 0; i < 2; ++i) {
            int flat = tid + i * 256;
            int arow = flat >> 2, af4 = flat & 3;
            int grow = m0 + arow;
            float4 a = (grow < NNODES)
                         ? *(const float4*)(X + (size_t)grow * 256 + k0 + af4 * 4)
                         : make_float4(0.f, 0.f, 0.f, 0.f);
            As[af4 * 4 + 0][arow] = a.x;
            As[af4 * 4 + 1][arow] = a.y;
            As[af4 * 4 + 2][arow] = a.z;
            As[af4 * 4 + 3][arow] = a.w;
        }
        // B tile: 16 k x 128 cols = 512 float4, 2 per thread
        #pragma unroll
        for (int i = 0; i < 2; ++i) {
            int flat = tid + i * 256;
            int brow = flat >> 5, bf4 = flat & 31;
            float4 b = *(const float4*)(W + (size_t)(k0 + brow) * 256 + n0 + bf4 * 4);
            *(float4*)&Bs[brow][bf4 * 4] = b;
        }
        __syncthreads();
        #pragma unroll
        for (int k = 0; k < 16; ++k) {
            float4 a0 = *(const float4*)&As[k][ty * 8];
            float4 a1 = *(const float4*)&As[k][ty * 8 + 4];
            float4 b0 = *(const float4*)&Bs[k][tx * 8];
            float4 b1 = *(const float4*)&Bs[k][tx * 8 + 4];
            float av[8] = {a0.x, a0.y, a0.z, a0.w, a1.x, a1.y, a1.z, a1.w};
            float bw[8] = {b0.x, b0.y, b0.z, b0.w, b1.x, b1.y, b1.z, b1.w};
            #pragma unroll
            for (int i = 0; i < 8; ++i)
                #pragma unroll
                for (int j = 0; j < 8; ++j)
                    acc[i][j] = fmaf(av[i], bw[j], acc[i][j]);
        }
        __syncthreads();
    }

    float bvals[8];
    #pragma unroll
    for (int j = 0; j < 8; ++j) bvals[j] = bias[n0 + tx * 8 + j];
    #pragma unroll
    for (int i = 0; i < 8; ++i) {
        int row = m0 + ty * 8 + i;
        if (row < NNODES) {
            float4 o0 = make_float4(acc[i][0] + bvals[0], acc[i][1] + bvals[1],
                                    acc[i][2] + bvals[2], acc[i][3] + bvals[3]);
            float4 o1 = make_float4(acc[i][4] + bvals[4], acc[i][5] + bvals[5],
                                    acc[i][6] + bvals[6], acc[i][7] + bvals[7]);
            *(float4*)(out + (size_t)row * 256 + n0 + tx * 8)     = o0;
            *(float4*)(out + (size_t)row * 256 + n0 + tx * 8 + 4) = o1;
        }
    }
}

// ---------------------------------------------------------------- attention
// one block per destination node; wave h (of 4) handles head h; lane = dim
__launch_bounds__(256, 4)
__global__ void attn_k(const float* __restrict__ q, const float* __restrict__ k,
                       const float* __restrict__ v, const float* __restrict__ s,
                       const int* __restrict__ off, const int* __restrict__ ssrc,
                       float* __restrict__ out) {
    const int node = blockIdx.x;
    const int h    = threadIdx.x >> 6;
    const int lane = threadIdx.x & 63;
    const int hd   = h * 64 + lane;

    const float qd = q[(size_t)node * 256 + hd];
    const int p0 = off[node], p1 = off[node + 1];

    float m = -3.0e38f, l = 0.f, acc = 0.f;
    for (int p = p0; p < p1; ++p) {
        int sn = ssrc[p];
        float kd = k[(size_t)sn * 256 + hd];
        float dot = qd * kd;
        #pragma unroll
        for (int o = 32; o >= 1; o >>= 1) dot += __shfl_xor(dot, o, 64);
        float score = dot * 0.125f;           // 1/sqrt(Dh)
        float nm = fmaxf(m, score);
        float sc = __expf(m - nm);
        float e  = __expf(score - nm);
        l   = l * sc + e;
        acc = acc * sc + e * v[(size_t)sn * 256 + hd];
        m = nm;
    }
    float o = (l > 0.f) ? acc / l : 0.f;
    out[(size_t)node * 256 + hd] = o + s[(size_t)node * 256 + hd];
}

// ---------------------------------------------------------------- batchnorm
__global__ void bn_stats(const float* __restrict__ y, float* __restrict__ colsum,
                         float* __restrict__ colsq) {
    int col = threadIdx.x;
    float sum = 0.f, sq = 0.f;
    for (int r = blockIdx.x; r < NNODES; r += gridDim.x) {
        float val = y[(size_t)r * 256 + col];
        sum += val;
        sq  += val * val;
    }
    atomicAdd(&colsum[col], sum);
    atomicAdd(&colsq[col], sq);
}

__global__ void bn_apply(const float* __restrict__ y, const float* __restrict__ colsum,
                         const float* __restrict__ colsq, const float* __restrict__ gamma,
                         const float* __restrict__ beta, float* __restrict__ xout) {
    int i4 = blockIdx.x * blockDim.x + threadIdx.x;
    if (i4 >= ND / 4) return;
    const float invN = 1.0f / NNODES;
    float4 yv = ((const float4*)y)[i4];
    int c0 = (i4 & 63) * 4;
    float yy[4] = {yv.x, yv.y, yv.z, yv.w};
    float o[4];
    #pragma unroll
    for (int j = 0; j < 4; ++j) {
        int c = c0 + j;
        float mean = colsum[c] * invN;
        float var  = colsq[c] * invN - mean * mean;
        float scl  = gamma[c] * rsqrtf(var + BN_EPS);
        float val  = (yy[j] - mean) * scl + beta[c];
        o[j] = fmaxf(val, 0.f);
    }
    ((float4*)xout)[i4] = make_float4(o[0], o[1], o[2], o[3]);
}

// ---------------------------------------------------------------- launch
extern "C" void kernel_launch(void* const* d_in, const int* in_sizes, int n_in,
                              void* d_out, int out_size, void* d_ws, size_t ws_size,
                              hipStream_t stream) {
    const float* x    = (const float*)d_in[0];
    const int*   ei   = (const int*)d_in[1];
    const float* Wq   = (const float*)d_in[2];
    const float* bq   = (const float*)d_in[3];
    const float* Wk   = (const float*)d_in[4];
    const float* bk   = (const float*)d_in[5];
    const float* Wv   = (const float*)d_in[6];
    const float* bv   = (const float*)d_in[7];
    const float* Ws   = (const float*)d_in[8];
    const float* bs   = (const float*)d_in[9];
    const float* bn_g = (const float*)d_in[10];
    const float* bn_b = (const float*)d_in[11];
    float* out = (float*)d_out;

    float* ws   = (float*)d_ws;
    float* q    = ws;
    float* kk   = ws + (size_t)ND;
    float* vv   = ws + 2 * (size_t)ND;
    float* ss   = ws + 3 * (size_t)ND;
    float* ybuf = ws + 4 * (size_t)ND;
    float* xbuf = ws + 5 * (size_t)ND;
    float* colstats = ws + 6 * (size_t)ND;           // 512 floats
    int* ip     = (int*)(colstats + 512);
    int* deg    = ip;
    int* offs   = ip + NNODES;                        // NNODES+1
    int* cursor = ip + 2 * NNODES + 1;
    int* ssrc   = ip + 3 * NNODES + 1;                // NEDGES
    const int* esrc = ei;
    const int* edst = ei + NEDGES;

    // CSR (dst-sorted) — rebuilt every call (ws is re-poisoned)
    zero_i<<<(NNODES + 255) / 256, 256, 0, stream>>>(deg, NNODES);
    hist_k<<<(NEDGES + 255) / 256, 256, 0, stream>>>(edst, deg);
    scan_k<<<1, 1024, 0, stream>>>(deg, offs, cursor);
    scatter_k<<<(NEDGES + 255) / 256, 256, 0, stream>>>(esrc, edst, cursor, ssrc);

    const float* xin = x;
    for (int l = 0; l < 3; ++l) {
        dim3 gg((NNODES + 127) / 128, 8);
        gemm_qkvs<<<gg, 256, 0, stream>>>(xin,
            Wq + (size_t)l * 65536, Wk + (size_t)l * 65536,
            Wv + (size_t)l * 65536, Ws + (size_t)l * 65536,
            bq + (size_t)l * 256, bk + (size_t)l * 256,
            bv + (size_t)l * 256, bs + (size_t)l * 256,
            q, kk, vv, ss);

        float* yout = (l == 2) ? out : ybuf;
        attn_k<<<NNODES, 256, 0, stream>>>(q, kk, vv, ss, offs, ssrc, yout);

        if (l < 2) {
            zero_f<<<2, 256, 0, stream>>>(colstats, 512);
            bn_stats<<<256, 256, 0, stream>>>(ybuf, colstats, colstats + 256);
            bn_apply<<<(ND / 4 + 255) / 256, 256, 0, stream>>>(
                ybuf, colstats, colstats + 256,
                bn_g + (size_t)l * 256, bn_b + (size_t)l * 256, xbuf);
            xin = xbuf;
        }
    }
}

// Round 2
// 1165.785 us; speedup vs baseline: 1.1026x; 1.1026x over previous
//
#include <hip/hip_runtime.h>
#include <hip/hip_bf16.h>

#define NNODES 20000
#define NEDGES 640000
#define DIM 256
#define ND (NNODES * DIM)
#define BN_EPS 1e-5f

// ---------------------------------------------------------------- utilities
__global__ void zero_i(int* __restrict__ p, int n) {
    int i = blockIdx.x * blockDim.x + threadIdx.x;
    if (i < n) p[i] = 0;
}
__global__ void zero_f(float* __restrict__ p, int n) {
    int i = blockIdx.x * blockDim.x + threadIdx.x;
    if (i < n) p[i] = 0.f;
}

// ---------------------------------------------------------------- CSR build
__global__ void hist_k(const int* __restrict__ dst, int* __restrict__ deg) {
    int e = blockIdx.x * blockDim.x + threadIdx.x;
    if (e < NEDGES) atomicAdd(&deg[dst[e]], 1);
}

__global__ void scan_k(const int* __restrict__ deg, int* __restrict__ off,
                       int* __restrict__ cursor) {
    __shared__ int sm[1024];
    __shared__ int carry_s;
    const int t = threadIdx.x;
    if (t == 0) carry_s = 0;
    __syncthreads();
    for (int base = 0; base < NNODES; base += 1024) {
        int i = base + t;
        int val = (i < NNODES) ? deg[i] : 0;
        sm[t] = val;
        __syncthreads();
        for (int ofs = 1; ofs < 1024; ofs <<= 1) {
            int add = (t >= ofs) ? sm[t - ofs] : 0;
            __syncthreads();
            sm[t] += add;
            __syncthreads();
        }
        int inc = sm[t];
        int carry = carry_s;
        int exc = carry + inc - val;
        if (i < NNODES) { off[i] = exc; cursor[i] = exc; }
        __syncthreads();
        if (t == 1023) carry_s = carry + sm[1023];
        __syncthreads();
    }
    if (t == 0) off[NNODES] = carry_s;
}

__global__ void scatter_k(const int* __restrict__ src, const int* __restrict__ dst,
                          int* __restrict__ cursor, int* __restrict__ ssrc) {
    int e = blockIdx.x * blockDim.x + threadIdx.x;
    if (e < NEDGES) {
        int d = dst[e];
        int pos = atomicAdd(&cursor[d], 1);
        ssrc[pos] = src[e];
    }
}

// ---------------------------------------------------------------- fused QKVS GEMM
// 128x128 C tile, BK=32, 256 threads, 8x8 microtile
__launch_bounds__(256, 2)
__global__ void gemm_qkvs(const float* __restrict__ X,
                          const float* __restrict__ Wq, const float* __restrict__ Wk,
                          const float* __restrict__ Wv, const float* __restrict__ Ws,
                          const float* __restrict__ bq, const float* __restrict__ bk,
                          const float* __restrict__ bv, const float* __restrict__ bs,
                          float* __restrict__ oq, float* __restrict__ ok,
                          float* __restrict__ ov, float* __restrict__ os) {
    __shared__ float As[32][132];   // [k][m], padded
    __shared__ float Bs[32][132];   // [k][n], padded

    const int mat = blockIdx.y >> 1;
    const int n0  = (blockIdx.y & 1) * 128;
    const int m0  = blockIdx.x * 128;

    const float* W    = (mat == 0) ? Wq : (mat == 1) ? Wk : (mat == 2) ? Wv : Ws;
    const float* bias = (mat == 0) ? bq : (mat == 1) ? bk : (mat == 2) ? bv : bs;
    float*       out  = (mat == 0) ? oq : (mat == 1) ? ok : (mat == 2) ? ov : os;

    const int tid = threadIdx.x;
    const int tx = tid & 15;
    const int ty = tid >> 4;

    float acc[8][8];
    #pragma unroll
    for (int i = 0; i < 8; ++i)
        #pragma unroll
        for (int j = 0; j < 8; ++j) acc[i][j] = 0.f;

    for (int k0 = 0; k0 < 256; k0 += 32) {
        // A tile: 128 rows x 32 k = 1024 float4, 4 per thread; store transposed
        #pragma unroll
        for (int i = 0; i < 4; ++i) {
            int flat = tid + i * 256;
            int arow = flat >> 3, af4 = flat & 7;
            int grow = m0 + arow;
            float4 a = (grow < NNODES)
                         ? *(const float4*)(X + (size_t)grow * 256 + k0 + af4 * 4)
                         : make_float4(0.f, 0.f, 0.f, 0.f);
            As[af4 * 4 + 0][arow] = a.x;
            As[af4 * 4 + 1][arow] = a.y;
            As[af4 * 4 + 2][arow] = a.z;
            As[af4 * 4 + 3][arow] = a.w;
        }
        // B tile: 32 k x 128 cols = 1024 float4
        #pragma unroll
        for (int i = 0; i < 4; ++i) {
            int flat = tid + i * 256;
            int brow = flat >> 5, bf4 = flat & 31;
            float4 b = *(const float4*)(W + (size_t)(k0 + brow) * 256 + n0 + bf4 * 4);
            *(float4*)&Bs[brow][bf4 * 4] = b;
        }
        __syncthreads();
        #pragma unroll
        for (int k = 0; k < 32; ++k) {
            float4 a0 = *(const float4*)&As[k][ty * 8];
            float4 a1 = *(const float4*)&As[k][ty * 8 + 4];
            float4 b0 = *(const float4*)&Bs[k][tx * 8];
            float4 b1 = *(const float4*)&Bs[k][tx * 8 + 4];
            float av[8] = {a0.x, a0.y, a0.z, a0.w, a1.x, a1.y, a1.z, a1.w};
            float bw[8] = {b0.x, b0.y, b0.z, b0.w, b1.x, b1.y, b1.z, b1.w};
            #pragma unroll
            for (int i = 0; i < 8; ++i)
                #pragma unroll
                for (int j = 0; j < 8; ++j)
                    acc[i][j] = fmaf(av[i], bw[j], acc[i][j]);
        }
        __syncthreads();
    }

    float bvals[8];
    #pragma unroll
    for (int j = 0; j < 8; ++j) bvals[j] = bias[n0 + tx * 8 + j];
    #pragma unroll
    for (int i = 0; i < 8; ++i) {
        int row = m0 + ty * 8 + i;
        if (row < NNODES) {
            float4 o0 = make_float4(acc[i][0] + bvals[0], acc[i][1] + bvals[1],
                                    acc[i][2] + bvals[2], acc[i][3] + bvals[3]);
            float4 o1 = make_float4(acc[i][4] + bvals[4], acc[i][5] + bvals[5],
                                    acc[i][6] + bvals[6], acc[i][7] + bvals[7]);
            *(float4*)(out + (size_t)row * 256 + n0 + tx * 8)     = o0;
            *(float4*)(out + (size_t)row * 256 + n0 + tx * 8 + 4) = o1;
        }
    }
}

// ---------------------------------------------------------------- attention
// block = 1 dst node, wave h = head h; wave split into 4 groups of 16 lanes,
// each group handles one edge per iteration with float4 loads (lane d4 holds
// dims 4*d4..4*d4+3). Online softmax with wave-shared running max; partial
// accumulators merged across groups at the end. Depth-1 prefetch of k/v.
__launch_bounds__(256, 4)
__global__ void attn_k(const float* __restrict__ q, const float* __restrict__ k,
                       const float* __restrict__ v, const float* __restrict__ s,
                       const int* __restrict__ off, const int* __restrict__ ssrc,
                       float* __restrict__ out) {
    const int node = blockIdx.x;
    const int h    = threadIdx.x >> 6;
    const int lane = threadIdx.x & 63;
    const int g    = lane >> 4;          // edge group 0..3
    const int d4   = lane & 15;          // float4 slot within head
    const size_t hoff = (size_t)h * 64 + (size_t)d4 * 4;

    const float4 qd = *(const float4*)(q + (size_t)node * 256 + hoff);
    const int p0 = off[node], p1 = off[node + 1];

    float m = -3.0e38f, l = 0.f;
    float4 acc = make_float4(0.f, 0.f, 0.f, 0.f);

    int p = p0 + g;
    bool valid = p < p1;
    int sn = valid ? ssrc[p] : 0;
    float4 kd = make_float4(0.f, 0.f, 0.f, 0.f), vd = kd;
    if (valid) {
        kd = *(const float4*)(k + (size_t)sn * 256 + hoff);
        vd = *(const float4*)(v + (size_t)sn * 256 + hoff);
    }

    while (__any(valid)) {
        // prefetch next edge (depth 1)
        int pn = p + 4;
        bool nvalid = pn < p1;
        float4 kdn = make_float4(0.f, 0.f, 0.f, 0.f), vdn = kdn;
        if (nvalid) {
            int snn = ssrc[pn];
            kdn = *(const float4*)(k + (size_t)snn * 256 + hoff);
            vdn = *(const float4*)(v + (size_t)snn * 256 + hoff);
        }

        // dot over Dh=64 within the 16-lane group
        float dot = qd.x * kd.x + qd.y * kd.y + qd.z * kd.z + qd.w * kd.w;
        dot += __shfl_xor(dot, 1, 64);
        dot += __shfl_xor(dot, 2, 64);
        dot += __shfl_xor(dot, 4, 64);
        dot += __shfl_xor(dot, 8, 64);
        float score = valid ? dot * 0.125f : -3.0e38f;

        // wave-wide max over 4 groups
        float smax = fmaxf(score, __shfl_xor(score, 16, 64));
        smax = fmaxf(smax, __shfl_xor(smax, 32, 64));
        float nm = fmaxf(m, smax);
        float scale = __expf(m - nm);
        float e = valid ? __expf(score - nm) : 0.f;
        float esum = e + __shfl_xor(e, 16, 64);
        esum += __shfl_xor(esum, 32, 64);
        l = l * scale + esum;
        acc.x = acc.x * scale + e * vd.x;
        acc.y = acc.y * scale + e * vd.y;
        acc.z = acc.z * scale + e * vd.z;
        acc.w = acc.w * scale + e * vd.w;
        m = nm;

        p = pn; valid = nvalid; kd = kdn; vd = vdn;
    }

    // merge partial accumulators across the 4 groups (same scale: shared m)
    acc.x += __shfl_xor(acc.x, 16, 64); acc.x += __shfl_xor(acc.x, 32, 64);
    acc.y += __shfl_xor(acc.y, 16, 64); acc.y += __shfl_xor(acc.y, 32, 64);
    acc.z += __shfl_xor(acc.z, 16, 64); acc.z += __shfl_xor(acc.z, 32, 64);
    acc.w += __shfl_xor(acc.w, 16, 64); acc.w += __shfl_xor(acc.w, 32, 64);

    if (g == 0) {
        float inv = (l > 0.f) ? 1.f / l : 0.f;
        float4 sv = *(const float4*)(s + (size_t)node * 256 + hoff);
        float4 o = make_float4(acc.x * inv + sv.x, acc.y * inv + sv.y,
                               acc.z * inv + sv.z, acc.w * inv + sv.w);
        *(float4*)(out + (size_t)node * 256 + hoff) = o;
    }
}

// ---------------------------------------------------------------- batchnorm
__global__ void bn_stats(const float* __restrict__ y, float* __restrict__ colsum,
                         float* __restrict__ colsq) {
    int col = threadIdx.x;
    float sum = 0.f, sq = 0.f;
    for (int r = blockIdx.x; r < NNODES; r += gridDim.x) {
        float val = y[(size_t)r * 256 + col];
        sum += val;
        sq  += val * val;
    }
    atomicAdd(&colsum[col], sum);
    atomicAdd(&colsq[col], sq);
}

__global__ void bn_apply(const float* __restrict__ y, const float* __restrict__ colsum,
                         const float* __restrict__ colsq, const float* __restrict__ gamma,
                         const float* __restrict__ beta, float* __restrict__ xout) {
    int i4 = blockIdx.x * blockDim.x + threadIdx.x;
    if (i4 >= ND / 4) return;
    const float invN = 1.0f / NNODES;
    float4 yv = ((const float4*)y)[i4];
    int c0 = (i4 & 63) * 4;
    float yy[4] = {yv.x, yv.y, yv.z, yv.w};
    float o[4];
    #pragma unroll
    for (int j = 0; j < 4; ++j) {
        int c = c0 + j;
        float mean = colsum[c] * invN;
        float var  = colsq[c] * invN - mean * mean;
        float scl  = gamma[c] * rsqrtf(var + BN_EPS);
        float val  = (yy[j] - mean) * scl + beta[c];
        o[j] = fmaxf(val, 0.f);
    }
    ((float4*)xout)[i4] = make_float4(o[0], o[1], o[2], o[3]);
}

// ---------------------------------------------------------------- launch
extern "C" void kernel_launch(void* const* d_in, const int* in_sizes, int n_in,
                              void* d_out, int out_size, void* d_ws, size_t ws_size,
                              hipStream_t stream) {
    const float* x    = (const float*)d_in[0];
    const int*   ei   = (const int*)d_in[1];
    const float* Wq   = (const float*)d_in[2];
    const float* bq   = (const float*)d_in[3];
    const float* Wk   = (const float*)d_in[4];
    const float* bk   = (const float*)d_in[5];
    const float* Wv   = (const float*)d_in[6];
    const float* bv   = (const float*)d_in[7];
    const float* Ws   = (const float*)d_in[8];
    const float* bs   = (const float*)d_in[9];
    const float* bn_g = (const float*)d_in[10];
    const float* bn_b = (const float*)d_in[11];
    float* out = (float*)d_out;

    float* ws   = (float*)d_ws;
    float* q    = ws;
    float* kk   = ws + (size_t)ND;
    float* vv   = ws + 2 * (size_t)ND;
    float* ss   = ws + 3 * (size_t)ND;
    float* ybuf = ws + 4 * (size_t)ND;
    float* xbuf = ws + 5 * (size_t)ND;
    float* colstats = ws + 6 * (size_t)ND;           // 512 floats
    int* ip     = (int*)(colstats + 512);
    int* deg    = ip;
    int* offs   = ip + NNODES;                        // NNODES+1
    int* cursor = ip + 2 * NNODES + 1;
    int* ssrc   = ip + 3 * NNODES + 1;                // NEDGES
    const int* esrc = ei;
    const int* edst = ei + NEDGES;

    zero_i<<<(NNODES + 255) / 256, 256, 0, stream>>>(deg, NNODES);
    hist_k<<<(NEDGES + 255) / 256, 256, 0, stream>>>(edst, deg);
    scan_k<<<1, 1024, 0, stream>>>(deg, offs, cursor);
    scatter_k<<<(NEDGES + 255) / 256, 256, 0, stream>>>(esrc, edst, cursor, ssrc);

    const float* xin = x;
    for (int l = 0; l < 3; ++l) {
        dim3 gg((NNODES + 127) / 128, 8);
        gemm_qkvs<<<gg, 256, 0, stream>>>(xin,
            Wq + (size_t)l * 65536, Wk + (size_t)l * 65536,
            Wv + (size_t)l * 65536, Ws + (size_t)l * 65536,
            bq + (size_t)l * 256, bk + (size_t)l * 256,
            bv + (size_t)l * 256, bs + (size_t)l * 256,
            q, kk, vv, ss);

        float* yout = (l == 2) ? out : ybuf;
        attn_k<<<NNODES, 256, 0, stream>>>(q, kk, vv, ss, offs, ssrc, yout);

        if (l < 2) {
            zero_f<<<2, 256, 0, stream>>>(colstats, 512);
            bn_stats<<<256, 256, 0, stream>>>(ybuf, colstats, colstats + 256);
            bn_apply<<<(ND / 4 + 255) / 256, 256, 0, stream>>>(
                ybuf, colstats, colstats + 256,
                bn_g + (size_t)l * 256, bn_b + (size_t)l * 256, xbuf);
            xin = xbuf;
        }
    }
}

// Round 3
// 1076.251 us; speedup vs baseline: 1.1944x; 1.0832x over previous
//
#include <hip/hip_runtime.h>
#include <hip/hip_bf16.h>

#define NNODES 20000
#define NEDGES 640000
#define DIM 256
#define ND (NNODES * DIM)
#define BN_EPS 1e-5f

typedef __bf16 bf16_t;
typedef __attribute__((ext_vector_type(8))) __bf16 bf16x8;
typedef __attribute__((ext_vector_type(4))) __bf16 bf16x4;
typedef __attribute__((ext_vector_type(4))) float f32x4;

// ---------------------------------------------------------------- utilities
__global__ void zero_i(int* __restrict__ p, int n) {
    int i = blockIdx.x * blockDim.x + threadIdx.x;
    if (i < n) p[i] = 0;
}
__global__ void zero_f(float* __restrict__ p, int n) {
    int i = blockIdx.x * blockDim.x + threadIdx.x;
    if (i < n) p[i] = 0.f;
}

// ---------------------------------------------------------------- CSR build
__global__ void hist_k(const int* __restrict__ dst, int* __restrict__ deg) {
    int e = blockIdx.x * blockDim.x + threadIdx.x;
    if (e < NEDGES) atomicAdd(&deg[dst[e]], 1);
}

__global__ void scan_k(const int* __restrict__ deg, int* __restrict__ off,
                       int* __restrict__ cursor) {
    __shared__ int sm[1024];
    __shared__ int carry_s;
    const int t = threadIdx.x;
    if (t == 0) carry_s = 0;
    __syncthreads();
    for (int base = 0; base < NNODES; base += 1024) {
        int i = base + t;
        int val = (i < NNODES) ? deg[i] : 0;
        sm[t] = val;
        __syncthreads();
        for (int ofs = 1; ofs < 1024; ofs <<= 1) {
            int add = (t >= ofs) ? sm[t - ofs] : 0;
            __syncthreads();
            sm[t] += add;
            __syncthreads();
        }
        int inc = sm[t];
        int carry = carry_s;
        int exc = carry + inc - val;
        if (i < NNODES) { off[i] = exc; cursor[i] = exc; }
        __syncthreads();
        if (t == 1023) carry_s = carry + sm[1023];
        __syncthreads();
    }
    if (t == 0) off[NNODES] = carry_s;
}

__global__ void scatter_k(const int* __restrict__ src, const int* __restrict__ dst,
                          int* __restrict__ cursor, int* __restrict__ ssrc) {
    int e = blockIdx.x * blockDim.x + threadIdx.x;
    if (e < NEDGES) {
        int d = dst[e];
        int pos = atomicAdd(&cursor[d], 1);
        ssrc[pos] = src[e];
    }
}

// ---------------------------------------------------------------- fp32 -> bf16 hi/lo split
__global__ void convx_k(const float* __restrict__ x, bf16_t* __restrict__ xhi,
                        bf16_t* __restrict__ xlo) {
    int i = blockIdx.x * blockDim.x + threadIdx.x;
    if (i >= ND / 4) return;
    float4 f = ((const float4*)x)[i];
    float ff[4] = {f.x, f.y, f.z, f.w};
    bf16x4 hv, lv;
    #pragma unroll
    for (int j = 0; j < 4; ++j) {
        bf16_t h = (bf16_t)ff[j];
        hv[j] = h;
        lv[j] = (bf16_t)(ff[j] - (float)h);
    }
    *(bf16x4*)(xhi + (size_t)i * 4) = hv;
    *(bf16x4*)(xlo + (size_t)i * 4) = lv;
}

// ---------------------------------------------------------------- W transpose + split
// input: W[l][k][col] fp32 (one of 4 arrays). output: Wt[matIdx][col][k] bf16 hi/lo
// grid (8 k-slabs, 12 matIdx), 256 threads
__global__ void convw_k(const float* __restrict__ Wq, const float* __restrict__ Wk,
                        const float* __restrict__ Wv, const float* __restrict__ Ws,
                        bf16_t* __restrict__ wthi, bf16_t* __restrict__ wtlo) {
    __shared__ float sm[32][257];
    const int matIdx = blockIdx.y;          // l*4 + mat
    const int l = matIdx >> 2, mat = matIdx & 3;
    const int k0 = blockIdx.x * 32;
    const int t = threadIdx.x;              // col
    const float* W = ((mat == 0) ? Wq : (mat == 1) ? Wk : (mat == 2) ? Wv : Ws)
                     + (size_t)l * 65536;
    for (int rr = 0; rr < 32; ++rr)
        sm[rr][t] = W[(size_t)(k0 + rr) * 256 + t];
    __syncthreads();
    size_t off = (size_t)matIdx * 65536 + (size_t)t * 256 + k0;
    #pragma unroll
    for (int c = 0; c < 4; ++c) {
        bf16x8 hv, lv;
        #pragma unroll
        for (int j = 0; j < 8; ++j) {
            float f = sm[c * 8 + j][t];
            bf16_t h = (bf16_t)f;
            hv[j] = h;
            lv[j] = (bf16_t)(f - (float)h);
        }
        *(bf16x8*)(wthi + off + c * 8) = hv;
        *(bf16x8*)(wtlo + off + c * 8) = lv;
    }
}

// ---------------------------------------------------------------- MFMA QKVS GEMM
// C = X @ W + b via split-bf16 (3-term). Barrier-free, LDS-free.
// grid (157, 8): y>>1 = mat, y&1 = col half. block 256 = 4 waves, 2x2 of 64x64.
__launch_bounds__(256, 2)
__global__ void gemm_mfma(const bf16_t* __restrict__ Xhi, const bf16_t* __restrict__ Xlo,
                          const bf16_t* __restrict__ Wthi, const bf16_t* __restrict__ Wtlo,
                          const float* __restrict__ bq, const float* __restrict__ bk,
                          const float* __restrict__ bv, const float* __restrict__ bs,
                          float* __restrict__ oq, float* __restrict__ ok,
                          float* __restrict__ ov, float* __restrict__ os) {
    const int mat = blockIdx.y >> 1;
    const int n0  = (blockIdx.y & 1) * 128;
    const int m0  = blockIdx.x * 128;

    const bf16_t* Whi = Wthi + (size_t)mat * 65536;
    const bf16_t* Wlo = Wtlo + (size_t)mat * 65536;
    const float* bias = (mat == 0) ? bq : (mat == 1) ? bk : (mat == 2) ? bv : bs;
    float*       out  = (mat == 0) ? oq : (mat == 1) ? ok : (mat == 2) ? ov : os;

    const int wid  = threadIdx.x >> 6;
    const int wr   = wid >> 1, wc = wid & 1;
    const int lane = threadIdx.x & 63;
    const int l15  = lane & 15, l4 = lane >> 4;

    f32x4 acc[4][4];
    #pragma unroll
    for (int i = 0; i < 4; ++i)
        #pragma unroll
        for (int j = 0; j < 4; ++j) acc[i][j] = (f32x4){0.f, 0.f, 0.f, 0.f};

    const bf16x8 zv = {};
    const int rowb = m0 + wr * 64 + l15;
    const int colb = n0 + wc * 64 + l15;

    for (int k0 = 0; k0 < 256; k0 += 32) {
        const int koff = k0 + l4 * 8;
        bf16x8 ah[4], al[4], bh[4], bl[4];
        #pragma unroll
        for (int f = 0; f < 4; ++f) {
            int row = rowb + f * 16;
            bool okr = row < NNODES;
            const bf16_t* pa = Xhi + (size_t)row * 256 + koff;
            const bf16_t* pl = Xlo + (size_t)row * 256 + koff;
            ah[f] = okr ? *(const bf16x8*)pa : zv;
            al[f] = okr ? *(const bf16x8*)pl : zv;
            int col = colb + f * 16;
            bh[f] = *(const bf16x8*)(Whi + (size_t)col * 256 + koff);
            bl[f] = *(const bf16x8*)(Wlo + (size_t)col * 256 + koff);
        }
        #pragma unroll
        for (int i = 0; i < 4; ++i)
            #pragma unroll
            for (int j = 0; j < 4; ++j) {
                acc[i][j] = __builtin_amdgcn_mfma_f32_16x16x32_bf16(ah[i], bh[j], acc[i][j], 0, 0, 0);
                acc[i][j] = __builtin_amdgcn_mfma_f32_16x16x32_bf16(ah[i], bl[j], acc[i][j], 0, 0, 0);
                acc[i][j] = __builtin_amdgcn_mfma_f32_16x16x32_bf16(al[i], bh[j], acc[i][j], 0, 0, 0);
            }
    }

    #pragma unroll
    for (int j = 0; j < 4; ++j) {
        int col = colb + j * 16;
        float b = bias[col];
        #pragma unroll
        for (int i = 0; i < 4; ++i) {
            int rbase = m0 + wr * 64 + i * 16 + l4 * 4;
            #pragma unroll
            for (int r = 0; r < 4; ++r) {
                int row = rbase + r;
                if (row < NNODES)
                    out[(size_t)row * 256 + col] = acc[i][j][r] + b;
            }
        }
    }
}

// ---------------------------------------------------------------- attention
// block = 1 dst node, wave h = head h; 8 groups of 8 lanes, each group owns
// one edge stream with a PRIVATE online softmax (m,l,acc); merged at the end.
// Lane d8 holds dims d8*8..d8*8+7 (32B loads). Depth-1 prefetch.
__launch_bounds__(256, 4)
__global__ void attn_k(const float* __restrict__ q, const float* __restrict__ k,
                       const float* __restrict__ v, const float* __restrict__ s,
                       const int* __restrict__ off, const int* __restrict__ ssrc,
                       float* __restrict__ out) {
    const int node = blockIdx.x;
    const int h    = threadIdx.x >> 6;
    const int lane = threadIdx.x & 63;
    const int g    = lane >> 3;          // group 0..7
    const int d8   = lane & 7;
    const size_t hoff = (size_t)h * 64 + (size_t)d8 * 8;

    const float4 q0 = *(const float4*)(q + (size_t)node * 256 + hoff);
    const float4 q1 = *(const float4*)(q + (size_t)node * 256 + hoff + 4);
    const int p0 = off[node], p1 = off[node + 1];

    float m = -3.0e38f, l = 0.f;
    float4 a0 = make_float4(0.f, 0.f, 0.f, 0.f), a1 = a0;

    int p = p0 + g;
    bool valid = p < p1;
    float4 k0v = make_float4(0.f, 0.f, 0.f, 0.f), k1v = k0v, v0v = k0v, v1v = k0v;
    if (valid) {
        int sn = ssrc[p];
        k0v = *(const float4*)(k + (size_t)sn * 256 + hoff);
        k1v = *(const float4*)(k + (size_t)sn * 256 + hoff + 4);
        v0v = *(const float4*)(v + (size_t)sn * 256 + hoff);
        v1v = *(const float4*)(v + (size_t)sn * 256 + hoff + 4);
    }

    while (__any(valid)) {
        int pn = p + 8;
        bool nvalid = pn < p1;
        float4 k0n = make_float4(0.f, 0.f, 0.f, 0.f), k1n = k0n, v0n = k0n, v1n = k0n;
        if (nvalid) {
            int snn = ssrc[pn];
            k0n = *(const float4*)(k + (size_t)snn * 256 + hoff);
            k1n = *(const float4*)(k + (size_t)snn * 256 + hoff + 4);
            v0n = *(const float4*)(v + (size_t)snn * 256 + hoff);
            v1n = *(const float4*)(v + (size_t)snn * 256 + hoff + 4);
        }

        float dot = q0.x * k0v.x + q0.y * k0v.y + q0.z * k0v.z + q0.w * k0v.w
                  + q1.x * k1v.x + q1.y * k1v.y + q1.z * k1v.z + q1.w * k1v.w;
        dot += __shfl_xor(dot, 1, 64);
        dot += __shfl_xor(dot, 2, 64);
        dot += __shfl_xor(dot, 4, 64);
        float score = valid ? dot * 0.125f : -3.0e38f;

        float nm = fmaxf(m, score);
        float sc = __expf(m - nm);
        float e  = valid ? __expf(score - nm) : 0.f;
        l = l * sc + e;
        a0.x = a0.x * sc + e * v0v.x;  a0.y = a0.y * sc + e * v0v.y;
        a0.z = a0.z * sc + e * v0v.z;  a0.w = a0.w * sc + e * v0v.w;
        a1.x = a1.x * sc + e * v1v.x;  a1.y = a1.y * sc + e * v1v.y;
        a1.z = a1.z * sc + e * v1v.z;  a1.w = a1.w * sc + e * v1v.w;
        m = nm;

        p = pn; valid = nvalid;
        k0v = k0n; k1v = k1n; v0v = v0n; v1v = v1n;
    }

    // merge the 8 groups
    float M = m;
    M = fmaxf(M, __shfl_xor(M, 8, 64));
    M = fmaxf(M, __shfl_xor(M, 16, 64));
    M = fmaxf(M, __shfl_xor(M, 32, 64));
    float r = (m > -1.0e37f) ? __expf(m - M) : 0.f;
    float lr = l * r;
    lr += __shfl_xor(lr, 8, 64);
    lr += __shfl_xor(lr, 16, 64);
    lr += __shfl_xor(lr, 32, 64);
    a0.x *= r; a0.y *= r; a0.z *= r; a0.w *= r;
    a1.x *= r; a1.y *= r; a1.z *= r; a1.w *= r;
    #pragma unroll
    for (int o = 8; o <= 32; o <<= 1) {
        a0.x += __shfl_xor(a0.x, o, 64); a0.y += __shfl_xor(a0.y, o, 64);
        a0.z += __shfl_xor(a0.z, o, 64); a0.w += __shfl_xor(a0.w, o, 64);
        a1.x += __shfl_xor(a1.x, o, 64); a1.y += __shfl_xor(a1.y, o, 64);
        a1.z += __shfl_xor(a1.z, o, 64); a1.w += __shfl_xor(a1.w, o, 64);
    }

    if (g == 0) {
        float inv = (lr > 0.f) ? 1.f / lr : 0.f;
        float4 s0 = *(const float4*)(s + (size_t)node * 256 + hoff);
        float4 s1 = *(const float4*)(s + (size_t)node * 256 + hoff + 4);
        float4 o0 = make_float4(a0.x * inv + s0.x, a0.y * inv + s0.y,
                                a0.z * inv + s0.z, a0.w * inv + s0.w);
        float4 o1 = make_float4(a1.x * inv + s1.x, a1.y * inv + s1.y,
                                a1.z * inv + s1.z, a1.w * inv + s1.w);
        *(float4*)(out + (size_t)node * 256 + hoff)     = o0;
        *(float4*)(out + (size_t)node * 256 + hoff + 4) = o1;
    }
}

// ---------------------------------------------------------------- batchnorm
__global__ void bn_stats(const float* __restrict__ y, float* __restrict__ colsum,
                         float* __restrict__ colsq) {
    int col = threadIdx.x;
    float sum = 0.f, sq = 0.f;
    for (int r = blockIdx.x; r < NNODES; r += gridDim.x) {
        float val = y[(size_t)r * 256 + col];
        sum += val;
        sq  += val * val;
    }
    atomicAdd(&colsum[col], sum);
    atomicAdd(&colsq[col], sq);
}

// BN + ReLU, emits next layer's input as bf16 hi/lo split
__global__ void bn_apply(const float* __restrict__ y, const float* __restrict__ colsum,
                         const float* __restrict__ colsq, const float* __restrict__ gamma,
                         const float* __restrict__ beta, bf16_t* __restrict__ xhi,
                         bf16_t* __restrict__ xlo) {
    int i4 = blockIdx.x * blockDim.x + threadIdx.x;
    if (i4 >= ND / 4) return;
    const float invN = 1.0f / NNODES;
    float4 yv = ((const float4*)y)[i4];
    int c0 = (i4 & 63) * 4;
    float yy[4] = {yv.x, yv.y, yv.z, yv.w};
    bf16x4 hv, lv;
    #pragma unroll
    for (int j = 0; j < 4; ++j) {
        int c = c0 + j;
        float mean = colsum[c] * invN;
        float var  = colsq[c] * invN - mean * mean;
        float scl  = gamma[c] * rsqrtf(var + BN_EPS);
        float val  = fmaxf((yy[j] - mean) * scl + beta[c], 0.f);
        bf16_t h = (bf16_t)val;
        hv[j] = h;
        lv[j] = (bf16_t)(val - (float)h);
    }
    *(bf16x4*)(xhi + (size_t)i4 * 4) = hv;
    *(bf16x4*)(xlo + (size_t)i4 * 4) = lv;
}

// ---------------------------------------------------------------- launch
extern "C" void kernel_launch(void* const* d_in, const int* in_sizes, int n_in,
                              void* d_out, int out_size, void* d_ws, size_t ws_size,
                              hipStream_t stream) {
    const float* x    = (const float*)d_in[0];
    const int*   ei   = (const int*)d_in[1];
    const float* Wq   = (const float*)d_in[2];
    const float* bq   = (const float*)d_in[3];
    const float* Wk   = (const float*)d_in[4];
    const float* bk   = (const float*)d_in[5];
    const float* Wv   = (const float*)d_in[6];
    const float* bv   = (const float*)d_in[7];
    const float* Ws   = (const float*)d_in[8];
    const float* bs   = (const float*)d_in[9];
    const float* bn_g = (const float*)d_in[10];
    const float* bn_b = (const float*)d_in[11];
    float* out = (float*)d_out;

    // workspace layout (all 16B aligned)
    float* ws   = (float*)d_ws;
    float* q    = ws;                          // ND f32
    float* kk   = ws + (size_t)ND;             // ND f32
    float* vv   = ws + 2 * (size_t)ND;         // ND f32
    float* ss   = ws + 3 * (size_t)ND;         // ND f32
    float* ybuf = ws + 4 * (size_t)ND;         // ND f32
    float* colstats = ws + 5 * (size_t)ND;     // 512 f32
    bf16_t* xhi  = (bf16_t*)(colstats + 512);  // ND bf16
    bf16_t* xlo  = xhi + (size_t)ND;           // ND bf16
    bf16_t* wthi = xlo + (size_t)ND;           // 12*65536 bf16
    bf16_t* wtlo = wthi + 12 * 65536;          // 12*65536 bf16
    int* ip     = (int*)(wtlo + 12 * 65536);
    int* deg    = ip;
    int* offs   = ip + NNODES;                 // NNODES+1
    int* cursor = ip + 2 * NNODES + 1;
    int* ssrc   = ip + 3 * NNODES + 1;         // NEDGES
    const int* esrc = ei;
    const int* edst = ei + NEDGES;

    // CSR (dst-sorted)
    zero_i<<<(NNODES + 255) / 256, 256, 0, stream>>>(deg, NNODES);
    hist_k<<<(NEDGES + 255) / 256, 256, 0, stream>>>(edst, deg);
    scan_k<<<1, 1024, 0, stream>>>(deg, offs, cursor);
    scatter_k<<<(NEDGES + 255) / 256, 256, 0, stream>>>(esrc, edst, cursor, ssrc);

    // one-time conversions
    convx_k<<<(ND / 4 + 255) / 256, 256, 0, stream>>>(x, xhi, xlo);
    convw_k<<<dim3(8, 12), 256, 0, stream>>>(Wq, Wk, Wv, Ws, wthi, wtlo);

    for (int l = 0; l < 3; ++l) {
        dim3 gg((NNODES + 127) / 128, 8);
        gemm_mfma<<<gg, 256, 0, stream>>>(xhi, xlo,
            wthi + (size_t)l * 4 * 65536, wtlo + (size_t)l * 4 * 65536,
            bq + (size_t)l * 256, bk + (size_t)l * 256,
            bv + (size_t)l * 256, bs + (size_t)l * 256,
            q, kk, vv, ss);

        float* yout = (l == 2) ? out : ybuf;
        attn_k<<<NNODES, 256, 0, stream>>>(q, kk, vv, ss, offs, ssrc, yout);

        if (l < 2) {
            zero_f<<<2, 256, 0, stream>>>(colstats, 512);
            bn_stats<<<256, 256, 0, stream>>>(ybuf, colstats, colstats + 256);
            bn_apply<<<(ND / 4 + 255) / 256, 256, 0, stream>>>(
                ybuf, colstats, colstats + 256,
                bn_g + (size_t)l * 256, bn_b + (size_t)l * 256, xhi, xlo);
        }
    }
}